// Round 10
// baseline (1329.839 us; speedup 1.0000x reference)
//
#include <hip/hip_runtime.h>
#include <hip/hip_bf16.h>
#include <cstdint>
#include <cstddef>

// ---------------------------------------------------------------------------
// EnrichAttention: B=32, L1=L2=512, H=A=256, 3H=768, 2H=512
// R10: MFMA GRU. 8 WGs x 256 thr; WG owns 4 batches. Each wave holds a
//      192x256 whh slice as 96 named bf16x8 SSA fragments (384 regs, AGPR
//      class via MFMA A-operands). Per step: h (bf16, LDS) -> 96 MFMAs ->
//      hp in LDS -> per-thread gates. Weights load ONCE (zero per-step
//      global weight traffic). GEMM pipeline identical to R5/R6/R8.
// ---------------------------------------------------------------------------

typedef short s8v __attribute__((ext_vector_type(8)));    // 8 bf16 (4 VGPRs)
typedef short s4v __attribute__((ext_vector_type(4)));    // 4 bf16
typedef float f4v __attribute__((ext_vector_type(4)));    // MFMA accumulator

#if __has_builtin(__builtin_amdgcn_sched_barrier)
#define SCHED_FENCE() __builtin_amdgcn_sched_barrier(0)
#else
#define SCHED_FENCE() asm volatile("" ::: "memory")
#endif

// Workgroup barrier waiting only on LDS (lgkmcnt): global loads (x prefetch)
// stay in flight across it. Only hlds/hpt (LDS) carry cross-thread deps.
__device__ __forceinline__ void bar_lds() {
    asm volatile("s_waitcnt lgkmcnt(0)\n\ts_barrier" ::: "memory");
}

__device__ __forceinline__ float fast_exp(float x) {
#if __has_builtin(__builtin_amdgcn_exp2f)
    return __builtin_amdgcn_exp2f(x * 1.44269504f);
#else
    return __expf(x);
#endif
}
__device__ __forceinline__ float fast_rcp(float x) {
#if __has_builtin(__builtin_amdgcn_rcpf)
    return __builtin_amdgcn_rcpf(x);
#else
    return 1.f / x;
#endif
}
__device__ __forceinline__ float fast_sig(float x) { return fast_rcp(1.f + fast_exp(-x)); }
__device__ __forceinline__ float fast_tanh(float x) {
    return 1.f - 2.f * fast_rcp(1.f + fast_exp(2.f * x));
}

__device__ __forceinline__ short f2bs(float f) {
    __hip_bfloat16 h = __float2bfloat16(f);
    return __builtin_bit_cast(short, h);
}

// ---------------------------------------------------------------------------
// MFMA bf16 NT GEMM (verified R5): C[M,N] = A[M,K] * B[N,K]^T.
// ---------------------------------------------------------------------------
__global__ __launch_bounds__(256) void gemm_bf16(
    const __hip_bfloat16* __restrict__ A, int lda, long long sA,
    const __hip_bfloat16* __restrict__ B, int ldb, long long sB,
    void* __restrict__ C, int ldc, long long sC,
    int K,
    const float* __restrict__ bias,
    const float* __restrict__ emul, int ldmul,
    int relu, int accum, int out_bf16)
{
    __shared__ short As[128][40];
    __shared__ short Bs[128][40];

    const int tid  = threadIdx.x;
    const int wave = tid >> 6, lane = tid & 63;
    const int quad = lane >> 4, l16 = lane & 15;
    const int wrow = (wave >> 1) * 64, wcol = (wave & 1) * 64;
    const int m0 = blockIdx.y * 128, n0 = blockIdx.x * 128;

    const short* Ab = (const short*)A + (size_t)blockIdx.z * sA;
    const short* Bb = (const short*)B + (size_t)blockIdx.z * sB;

    f4v acc[4][4];
#pragma unroll
    for (int i = 0; i < 4; ++i)
#pragma unroll
        for (int j = 0; j < 4; ++j) acc[i][j] = 0.f;

    const int r0 = tid >> 2,        s0 = (tid & 3) * 8;
    const int r1 = (tid + 256) >> 2, s1 = ((tid + 256) & 3) * 8;

    for (int k0 = 0; k0 < K; k0 += 32) {
        *(s8v*)&As[r0][s0] = *(const s8v*)(Ab + (size_t)(m0 + r0) * lda + k0 + s0);
        *(s8v*)&As[r1][s1] = *(const s8v*)(Ab + (size_t)(m0 + r1) * lda + k0 + s1);
        *(s8v*)&Bs[r0][s0] = *(const s8v*)(Bb + (size_t)(n0 + r0) * ldb + k0 + s0);
        *(s8v*)&Bs[r1][s1] = *(const s8v*)(Bb + (size_t)(n0 + r1) * ldb + k0 + s1);
        __syncthreads();

        s8v af[4], bf[4];
#pragma unroll
        for (int i = 0; i < 4; ++i)
            af[i] = *(const s8v*)&As[wrow + i * 16 + l16][quad * 8];
#pragma unroll
        for (int j = 0; j < 4; ++j)
            bf[j] = *(const s8v*)&Bs[wcol + j * 16 + l16][quad * 8];
#pragma unroll
        for (int i = 0; i < 4; ++i)
#pragma unroll
            for (int j = 0; j < 4; ++j)
                acc[i][j] = __builtin_amdgcn_mfma_f32_16x16x32_bf16(
                    af[i], bf[j], acc[i][j], 0, 0, 0);
        __syncthreads();
    }

    float* Cf = (float*)C + (size_t)blockIdx.z * sC;
    __hip_bfloat16* Cb = (__hip_bfloat16*)C + (size_t)blockIdx.z * sC;
#pragma unroll
    for (int i = 0; i < 4; ++i)
#pragma unroll
        for (int j = 0; j < 4; ++j)
#pragma unroll
            for (int r = 0; r < 4; ++r) {
                const int m = m0 + wrow + i * 16 + quad * 4 + r;
                const int n = n0 + wcol + j * 16 + l16;
                float v = acc[i][j][r];
                if (bias)  v += bias[n];
                if (accum) v += Cf[(size_t)m * ldc + n];
                if (emul)  v *= emul[(size_t)m * ldmul + n];
                if (relu)  v = fmaxf(v, 0.f);
                if (out_bf16) Cb[(size_t)m * ldc + n] = __float2bfloat16(v);
                else          Cf[(size_t)m * ldc + n] = v;
            }
}

// fp32 -> bf16 elementwise (n % 4 == 0)
__global__ __launch_bounds__(256) void f2b(
    const float* __restrict__ s, __hip_bfloat16* __restrict__ d, int n)
{
    const int i = (blockIdx.x * 256 + threadIdx.x) * 4;
    if (i < n) {
        float4 v = *(const float4*)(s + i);
        d[i + 0] = __float2bfloat16(v.x);
        d[i + 1] = __float2bfloat16(v.y);
        d[i + 2] = __float2bfloat16(v.z);
        d[i + 3] = __float2bfloat16(v.w);
    }
}

// fp32 [Z][R][C] -> bf16 [Z][C][R] tiled transpose
__global__ __launch_bounds__(256) void tr_f2b(
    const float* __restrict__ src, __hip_bfloat16* __restrict__ dst,
    int R, int C, long long sS, long long sD)
{
    __shared__ float t[32][33];
    const int r0 = blockIdx.y * 32, c0 = blockIdx.x * 32;
    const int tx = threadIdx.x & 31, ty = threadIdx.x >> 5;
    const float* S = src + (size_t)blockIdx.z * sS;
    __hip_bfloat16* Dd = dst + (size_t)blockIdx.z * sD;
#pragma unroll
    for (int i = 0; i < 32; i += 8)
        t[ty + i][tx] = S[(size_t)(r0 + ty + i) * C + c0 + tx];
    __syncthreads();
#pragma unroll
    for (int i = 0; i < 32; i += 8)
        Dd[(size_t)(c0 + ty + i) * R + r0 + tx] = __float2bfloat16(t[tx][ty + i]);
}

// softmax over axis=1 (i) for each (b, j): fp32 in, bf16 out
__global__ __launch_bounds__(256) void softmax_dim1(
    const float* __restrict__ Mf, __hip_bfloat16* __restrict__ Ms)
{
    const int j = blockIdx.x * 256 + threadIdx.x;
    const float* base = Mf + (size_t)blockIdx.y * 262144;
    __hip_bfloat16* ob = Ms + (size_t)blockIdx.y * 262144;

    float mx = -1e30f;
    for (int i = 0; i < 512; ++i)
        mx = fmaxf(mx, base[(size_t)i * 512 + j]);
    float s = 0.f;
    for (int i = 0; i < 512; ++i)
        s += __expf(base[(size_t)i * 512 + j] - mx);
    const float inv = 1.f / s;
    for (int i = 0; i < 512; ++i)
        ob[(size_t)i * 512 + j] =
            __float2bfloat16(__expf(base[(size_t)i * 512 + j] - mx) * inv);
}

// ---------------------------------------------------------------------------
// GRU R10 (MFMA). 8 WGs x 256 threads; WG g owns batches 4g..4g+3.
// Wave w holds whh rows [192w, 192w+192) as 96 named s8v fragments.
// A-frag layout (HW-verified): A[m=lane&15][k=quad*8+j].
// C-frag layout: col(batch)=lane&15, row=quad*4+r (+16*tile).
// hlds[16][264] bf16: h rows 0..3 live, 4..15 stay zero (unused MFMA cols).
// hpt[16][776] fp32: hp, [batch][row] with pad for bank spread.
// ---------------------------------------------------------------------------
#define GRU_LW(I,T) s8v W_##I##_##T; { \
    const float* p_ = wbasep + (I)*4096 + (T)*32; \
    float4 q0_ = *(const float4*)(p_); \
    float4 q1_ = *(const float4*)(p_ + 4); \
    W_##I##_##T[0]=f2bs(q0_.x); W_##I##_##T[1]=f2bs(q0_.y); \
    W_##I##_##T[2]=f2bs(q0_.z); W_##I##_##T[3]=f2bs(q0_.w); \
    W_##I##_##T[4]=f2bs(q1_.x); W_##I##_##T[5]=f2bs(q1_.y); \
    W_##I##_##T[6]=f2bs(q1_.z); W_##I##_##T[7]=f2bs(q1_.w); }

#define GRU_LWI(I) \
    GRU_LW(I,0) GRU_LW(I,1) GRU_LW(I,2) GRU_LW(I,3) \
    GRU_LW(I,4) GRU_LW(I,5) GRU_LW(I,6) GRU_LW(I,7) SCHED_FENCE();

#define GRU_MFI(I) { \
    f4v a_ = {0.f, 0.f, 0.f, 0.f}; \
    a_ = __builtin_amdgcn_mfma_f32_16x16x32_bf16(W_##I##_0, B0, a_, 0,0,0); \
    a_ = __builtin_amdgcn_mfma_f32_16x16x32_bf16(W_##I##_1, B1, a_, 0,0,0); \
    a_ = __builtin_amdgcn_mfma_f32_16x16x32_bf16(W_##I##_2, B2, a_, 0,0,0); \
    a_ = __builtin_amdgcn_mfma_f32_16x16x32_bf16(W_##I##_3, B3, a_, 0,0,0); \
    a_ = __builtin_amdgcn_mfma_f32_16x16x32_bf16(W_##I##_4, B4, a_, 0,0,0); \
    a_ = __builtin_amdgcn_mfma_f32_16x16x32_bf16(W_##I##_5, B5, a_, 0,0,0); \
    a_ = __builtin_amdgcn_mfma_f32_16x16x32_bf16(W_##I##_6, B6, a_, 0,0,0); \
    a_ = __builtin_amdgcn_mfma_f32_16x16x32_bf16(W_##I##_7, B7, a_, 0,0,0); \
    if (l16 < 4) *(f4v*)&hpt[l16][wrow + (I)*16 + q4] = a_; }

__global__ __launch_bounds__(256, 1) void gru_kernel(
    const float* __restrict__ xproj,   // [B, T, 768] fp32
    const float* __restrict__ whh,     // [768, 256] fp32
    const float* __restrict__ bhh,     // [768]
    float* __restrict__ out)           // [B, T, 256] fp32
{
    const int tid  = threadIdx.x;
    const int lane = tid & 63;
    const int l16  = lane & 15, quad = lane >> 4;
    const int q8 = quad * 8, q4 = quad * 4;
    const int w    = tid >> 6;          // wave 0..3
    const int wrow = w * 192;

    __shared__ short hlds[16][264];     // h state, bf16, padded rows
    __shared__ float hpt[16][776];      // hp: [batch][row 0..767], padded

    // ---- weight preload: 96 named fragments (wave w, rows wrow..wrow+191)
    const float* wbasep = whh + (size_t)(wrow + l16) * 256 + q8;
    GRU_LWI(0)  GRU_LWI(1)  GRU_LWI(2)  GRU_LWI(3)
    GRU_LWI(4)  GRU_LWI(5)  GRU_LWI(6)  GRU_LWI(7)
    GRU_LWI(8)  GRU_LWI(9)  GRU_LWI(10) GRU_LWI(11)

    // ---- gate-phase identity: batch b (0..3), dims dd..dd+3
    const int b  = tid >> 6;            // == w
    const int dd = (tid & 63) * 4;
    const int gb = blockIdx.x * 4 + b;  // global batch
    const float* xb = xproj + (size_t)gb * 512 * 768;
    float* ob = out + (size_t)gb * 512 * 256;

    const float4 bhr = *(const float4*)&bhh[dd];
    const float4 bhz = *(const float4*)&bhh[256 + dd];
    const float4 bhn = *(const float4*)&bhh[512 + dd];

    // zero h buffer (rows 4..15 stay zero forever -> dead MFMA columns)
    for (int i = tid; i < 16 * 264; i += 256) ((short*)hlds)[i] = 0;

    float4 hp4 = make_float4(0.f, 0.f, 0.f, 0.f);   // h_prev for (b, dd..dd+3)
    bar_lds();

    for (int t = 0; t < 512; ++t) {
        // x prefetch for this step (global; survives lgkm-only barriers)
        const float* xrow = xb + (size_t)t * 768;
        const float4 xr4 = *(const float4*)(xrow + dd);
        const float4 xz4 = *(const float4*)(xrow + 256 + dd);
        const float4 xn4 = *(const float4*)(xrow + 512 + dd);

        // B-fragments from h: B[n=batch=l16][k=32T+q8..+7]
        s8v B0 = *(const s8v*)&hlds[l16][0 * 32 + q8];
        s8v B1 = *(const s8v*)&hlds[l16][1 * 32 + q8];
        s8v B2 = *(const s8v*)&hlds[l16][2 * 32 + q8];
        s8v B3 = *(const s8v*)&hlds[l16][3 * 32 + q8];
        s8v B4 = *(const s8v*)&hlds[l16][4 * 32 + q8];
        s8v B5 = *(const s8v*)&hlds[l16][5 * 32 + q8];
        s8v B6 = *(const s8v*)&hlds[l16][6 * 32 + q8];
        s8v B7 = *(const s8v*)&hlds[l16][7 * 32 + q8];

        GRU_MFI(0)  GRU_MFI(1)  GRU_MFI(2)  GRU_MFI(3)
        GRU_MFI(4)  GRU_MFI(5)  GRU_MFI(6)  GRU_MFI(7)
        GRU_MFI(8)  GRU_MFI(9)  GRU_MFI(10) GRU_MFI(11)

        bar_lds();   // hp visible; everyone done reading h(t)

        // ---- gates for (batch b, dims dd..dd+3)
        {
            const float4 hr4 = *(const float4*)&hpt[b][dd];
            const float4 hz4 = *(const float4*)&hpt[b][256 + dd];
            const float4 hn4 = *(const float4*)&hpt[b][512 + dd];

            float r0 = fast_sig(xr4.x + bhr.x + hr4.x);
            float r1 = fast_sig(xr4.y + bhr.y + hr4.y);
            float r2 = fast_sig(xr4.z + bhr.z + hr4.z);
            float r3 = fast_sig(xr4.w + bhr.w + hr4.w);
            float z0 = fast_sig(xz4.x + bhz.x + hz4.x);
            float z1 = fast_sig(xz4.y + bhz.y + hz4.y);
            float z2 = fast_sig(xz4.z + bhz.z + hz4.z);
            float z3 = fast_sig(xz4.w + bhz.w + hz4.w);
            float n0 = fast_tanh(xn4.x + r0 * (bhn.x + hn4.x));
            float n1 = fast_tanh(xn4.y + r1 * (bhn.y + hn4.y));
            float n2 = fast_tanh(xn4.z + r2 * (bhn.z + hn4.z));
            float n3 = fast_tanh(xn4.w + r3 * (bhn.w + hn4.w));
            float h0 = (1.f - z0) * n0 + z0 * hp4.x;
            float h1 = (1.f - z1) * n1 + z1 * hp4.y;
            float h2 = (1.f - z2) * n2 + z2 * hp4.z;
            float h3 = (1.f - z3) * n3 + z3 * hp4.w;
            hp4 = make_float4(h0, h1, h2, h3);

            *(float4*)(ob + (size_t)t * 256 + dd) = hp4;
            s4v hw; hw[0] = f2bs(h0); hw[1] = f2bs(h1);
            hw[2] = f2bs(h2); hw[3] = f2bs(h3);
            *(s4v*)&hlds[b][dd] = hw;
        }
        bar_lds();   // new h visible for next step's B-frags
    }
}
#undef GRU_MFI
#undef GRU_LWI
#undef GRU_LW

extern "C" void kernel_launch(void* const* d_in, const int* in_sizes, int n_in,
                              void* d_out, int out_size, void* d_ws, size_t ws_size,
                              hipStream_t stream)
{
    (void)in_sizes; (void)n_in; (void)out_size; (void)ws_size;

    const float* x1  = (const float*)d_in[0];   // [32,512,256]
    const float* x2  = (const float*)d_in[1];   // [32,512,256]
    const float* w1  = (const float*)d_in[2];   // [256,256]
    const float* w2  = (const float*)d_in[3];   // [256,256]
    const float* Dm  = (const float*)d_in[4];   // [256,256]
    const float* Wm  = (const float*)d_in[5];   // [512,512]
    const float* wih = (const float*)d_in[6];   // [768,512]
    const float* whh = (const float*)d_in[7];   // [768,256]
    const float* bih = (const float*)d_in[8];   // [768]
    const float* bhh = (const float*)d_in[9];   // [768]
    float* out = (float*)d_out;

    // Workspace aliasing identical to the passing R5/R6/R8.
    char* base = (char*)d_ws;
    __hip_bfloat16* w1b  = (__hip_bfloat16*)(base + 0);
    __hip_bfloat16* w2b  = (__hip_bfloat16*)(base + 131072);
    __hip_bfloat16* Dtb  = (__hip_bfloat16*)(base + 262144);
    float*          Mf   = (float*)(base + 0);
    float*          xp   = (float*)(base + 0);
    __hip_bfloat16* a1b  = (__hip_bfloat16*)(base + 33554432);
    __hip_bfloat16* a1db = (__hip_bfloat16*)(base + 41943040);
    __hip_bfloat16* Msb  = (__hip_bfloat16*)(base + 33554432);
    __hip_bfloat16* x1b  = (__hip_bfloat16*)(base + 50331648);
    __hip_bfloat16* x2b  = (__hip_bfloat16*)(base + 58720256);
    __hip_bfloat16* ctxb = (__hip_bfloat16*)(base + 58720256);
    __hip_bfloat16* x2tb = (__hip_bfloat16*)(base + 67108864);
    __hip_bfloat16* a2b  = (__hip_bfloat16*)(base + 75497472);
    __hip_bfloat16* wihb = (__hip_bfloat16*)(base + 75497472);

    dim3 blk(256);

    f2b<<<dim3(4096), blk, 0, stream>>>(x1, x1b, 4194304);
    f2b<<<dim3(4096), blk, 0, stream>>>(x2, x2b, 4194304);
    f2b<<<dim3(64),   blk, 0, stream>>>(w1, w1b, 65536);
    f2b<<<dim3(64),   blk, 0, stream>>>(w2, w2b, 65536);
    tr_f2b<<<dim3(8, 16, 32), blk, 0, stream>>>(x2, x2tb, 512, 256, 131072, 131072);
    tr_f2b<<<dim3(8, 8, 1),   blk, 0, stream>>>(Dm, Dtb, 256, 256, 0, 0);

    gemm_bf16<<<dim3(2, 128, 1), blk, 0, stream>>>(
        x1b, 256, 0, w1b, 256, 0, a1b, 256, 0, 256,
        nullptr, nullptr, 0, 1, 0, 1);
    gemm_bf16<<<dim3(2, 128, 1), blk, 0, stream>>>(
        x2b, 256, 0, w2b, 256, 0, a2b, 256, 0, 256,
        nullptr, nullptr, 0, 1, 0, 1);
    gemm_bf16<<<dim3(2, 128, 1), blk, 0, stream>>>(
        a1b, 256, 0, Dtb, 256, 0, a1db, 256, 0, 256,
        nullptr, nullptr, 0, 0, 0, 1);
    gemm_bf16<<<dim3(4, 4, 32), blk, 0, stream>>>(
        a1db, 256, 131072, a2b, 256, 131072, Mf, 512, 262144, 256,
        nullptr, Wm, 512, 0, 0, 0);
    f2b<<<dim3(384), blk, 0, stream>>>(wih, wihb, 393216);
    softmax_dim1<<<dim3(2, 32), blk, 0, stream>>>(Mf, Msb);
    gemm_bf16<<<dim3(2, 4, 32), blk, 0, stream>>>(
        Msb, 512, 262144, x2tb, 512, 131072, ctxb, 256, 131072, 512,
        nullptr, nullptr, 0, 0, 0, 1);
    gemm_bf16<<<dim3(6, 128, 1), blk, 0, stream>>>(
        x1b, 256, 0, wihb, 512, 0, xp, 768, 0, 256,
        bih, nullptr, 0, 0, 0, 0);
    gemm_bf16<<<dim3(6, 128, 1), blk, 0, stream>>>(
        ctxb, 256, 0, wihb + 256, 512, 0, xp, 768, 0, 256,
        nullptr, nullptr, 0, 0, 1, 0);
    // MFMA GRU: 8 WGs x 256 threads, 4 batches per WG
    gru_kernel<<<dim3(8), dim3(256), 0, stream>>>(xp, whh, bhh, out);
}